// Round 22
// baseline (24.484 us; speedup 1.0000x reference)
//
#include <hip/hip_runtime.h>

// Problem constants (fixed by setup_inputs)
#define K   19
#define C   256
#define HF  64
#define WF  128
#define HW  (HF * WF)
#define BB  4
#define HL  512
#define WL  1024

// bf16-split-x3 distance error bound ~1e-3 worst-case; pixels whose top-2
// gap < TAU get the proven exact-f64 cooperative resolve.
#define TAU 0.03f

#define CPAD 264                      // halfwords per centroid row
#define DPAD 66                       // dwords per acc row
#define CHI_BYTES  (K * CPAD * 2)     // 10032 B
#define DBUF_BYTES (8 * 16 * DPAD * 4)// 33792 B  (2 tiles x 4 khq x 16 reg)
#define POOL_BYTES 33792              // max(2*CHI_BYTES=20064, DBUF) -> overlay

typedef __attribute__((ext_vector_type(8)))  short bf16x8;
typedef __attribute__((ext_vector_type(16))) float f32x16;

// R19 structure at 2x the wave count, confounds removed (vs R21):
//  - 512 thr = 8 waves = 2 tiles x 4 K-quarters, still 64 px/block ->
//    1024 blocks (same centroid staging cost as R19) but 8192 waves
//    = 8 waves/SIMD (R19 was work-limited at 4).
//  - dbuf (33.8 KB) OVERLAYS the dead chi/clo pool -> ~35 KB/block,
//    4 blocks/CU resident.
//  - 2-deep register prefetch (named fvA/fvB, static): step s+1's loads
//    issue before step s's pack/MFMA consumes.
//  - B-fragment base includes khq*64 (R18 lesson: kh offset in BOTH A,B).
// Epilogue + exact-f64 cooperative fallback: R19 verbatim, 4-term kh merge.
__global__ __launch_bounds__(512, 8) void centroid_mask_kernel(
    const float* __restrict__ feat0,   // feature_s2t
    const float* __restrict__ feat1,   // feature_target
    const float* __restrict__ cent0,   // centroids for map 0 (centroid_target)
    const float* __restrict__ cent1,   // centroids for map 1 (centroid_s2t)
    int* __restrict__ out)             // [2][BB][HL][WL] int32
{
    __shared__ __align__(16) unsigned char pool[POOL_BYTES];  // chi|clo -> dbuf
    __shared__ double c2p[K][8];             // exact ||c||^2 partials
    __shared__ double sc2d[K];               // exact ||c||^2 (f64)
    __shared__ float  sc2f[K];               // rounded-exact ||c||^2 (f32)

    unsigned short* __restrict__ chi = (unsigned short*)pool;
    unsigned short* __restrict__ clo = (unsigned short*)(pool + CHI_BYTES);
    float*          __restrict__ dbf = (float*)pool;   // overlay after MFMA

    const int map = blockIdx.y;
    const float* __restrict__ feat = (map == 0) ? feat0 : feat1;
    const float* __restrict__ cent = (map == 0) ? cent0 : cent1;

    const int tid  = threadIdx.x;
    const int lane = tid & 63;
    const int wv   = __builtin_amdgcn_readfirstlane(tid >> 6);   // 0..7
    const int tile = wv >> 2;                  // 0..1
    const int khq  = wv & 3;                   // K-quarter: 0..3

    // ---- stage split centroids into LDS (coalesced) + exact ||c||^2 ----
    for (int i = tid; i < K * C; i += 512) {
        const int k = i >> 8, c = i & (C - 1);
        const unsigned u = __float_as_uint(cent[i]);
        const float r = __uint_as_float(u) - __uint_as_float(u & 0xffff0000u);
        chi[k * CPAD + c] = (unsigned short)(u >> 16);
        clo[k * CPAD + c] = (unsigned short)(__float_as_uint(r) >> 16);
    }
    if (tid < K * 8) {
        const int k = tid >> 3, sl = tid & 7;
        const float* cp = cent + k * C + sl * 32;
        double s = 0.0;
        #pragma unroll
        for (int j = 0; j < 32; ++j) { double v = (double)cp[j]; s = fma(v, v, s); }
        c2p[k][sl] = s;
    }
    __syncthreads();
    if (tid < K) {
        double s = 0.0;
        #pragma unroll
        for (int j = 0; j < 8; ++j) s += c2p[tid][j];
        sc2d[tid] = s;
        sc2f[tid] = (float)s;
    }

    // ---- main: wave = (tile, khq); 32 px x 19 k over 64 channels ----
    const int hl2  = (lane >> 5) & 1;              // k-subchunk select
    const int pp   = blockIdx.x * 64 + tile * 32 + (lane & 31);
    const int hw   = pp & (HW - 1);
    const int b    = pp >> 13;

    const float* __restrict__ fp = feat + (size_t)b * C * HW + hw;
    const int cb0  = khq * 64 + hl2 * 8;           // A channel base
    const int bidx = min(lane & 31, 18) * CPAD + khq * 64 + hl2 * 8;  // B base

    f32x16 acc;
    #pragma unroll
    for (int r = 0; r < 16; ++r) acc[r] = 0.f;

    float fvA[8], fvB[8];

#define LOADS(buf, s)                                                   \
    {                                                                   \
        _Pragma("unroll")                                               \
        for (int j = 0; j < 8; ++j)                                     \
            buf[j] = fp[(size_t)(cb0 + (s) * 16 + j) * HW];             \
    }
#define STEP(buf, s)                                                    \
    {                                                                   \
        union { unsigned u[4]; bf16x8 v; } ah, al, bh, bl;              \
        _Pragma("unroll")                                               \
        for (int j = 0; j < 4; ++j) {                                   \
            const unsigned u0 = __float_as_uint(buf[2*j]);              \
            const unsigned u1 = __float_as_uint(buf[2*j+1]);            \
            ah.u[j] = (u0 >> 16) | (u1 & 0xffff0000u);                  \
            const float r0 = buf[2*j]   - __uint_as_float(u0 & 0xffff0000u); \
            const float r1 = buf[2*j+1] - __uint_as_float(u1 & 0xffff0000u); \
            al.u[j] = (__float_as_uint(r0) >> 16)                       \
                    | (__float_as_uint(r1) & 0xffff0000u);              \
        }                                                               \
        bh.v = *(const bf16x8*)&chi[bidx + (s) * 16];                   \
        bl.v = *(const bf16x8*)&clo[bidx + (s) * 16];                   \
        acc = __builtin_amdgcn_mfma_f32_32x32x16_bf16(ah.v, bh.v, acc, 0, 0, 0); \
        acc = __builtin_amdgcn_mfma_f32_32x32x16_bf16(ah.v, bl.v, acc, 0, 0, 0); \
        acc = __builtin_amdgcn_mfma_f32_32x32x16_bf16(al.v, bh.v, acc, 0, 0, 0); \
    }

    // 2-deep software pipeline over the 4 K-steps
    LOADS(fvA, 0)
    LOADS(fvB, 1)
    STEP(fvA, 0) LOADS(fvA, 2)
    STEP(fvB, 1) LOADS(fvB, 3)
    STEP(fvA, 2)
    STEP(fvB, 3)

#undef LOADS
#undef STEP

    __syncthreads();   // all waves done READING chi/clo -> pool reusable

    // dump acc into overlay: (reg,lane) = D[px=(reg&3)+8(reg>>2)+4(lane>>5)][k=lane&31]
    {
        float* dst = &dbf[((tile * 4 + khq) * 16) * DPAD + hl2 * 32 + (lane & 31)];
        #pragma unroll
        for (int r = 0; r < 16; ++r) dst[r * DPAD] = acc[r];
    }
    __syncthreads();

    // ---- epilogue: wave 0, lane = pixel (both tiles); R19 pattern verbatim ----
    if (tid < 64) {
        const int l   = tid;
        const int tl  = l >> 5, px = l & 31;
        const int h   = (px >> 2) & 1;
        const int reg = (px & 3) | ((px >> 3) << 2);
        const int bse = h * 32;

        const int ppx = blockIdx.x * 64 + l;       // tl*32+px == l
        const int phw = ppx & (HW - 1);
        const int pb  = ppx >> 13;

        float d[K];
        #pragma unroll
        for (int k = 0; k < K; ++k) {
            const float s = (dbf[((tl*4+0)*16 + reg) * DPAD + bse + k]
                           + dbf[((tl*4+1)*16 + reg) * DPAD + bse + k])
                          + (dbf[((tl*4+2)*16 + reg) * DPAD + bse + k]
                           + dbf[((tl*4+3)*16 + reg) * DPAD + bse + k]);
            d[k] = sc2f[k] - 2.0f * s;
        }
        int best = 0; float m1 = d[0];
        #pragma unroll
        for (int k = 1; k < K; ++k) if (d[k] < m1) { m1 = d[k]; best = k; }

        unsigned cmask = 0u;
        #pragma unroll
        for (int k = 0; k < K; ++k) if (d[k] - m1 < TAU) cmask |= (1u << k);

        // cooperative exact-f64 resolve of flagged pixels (proven, R8)
        const bool need = (cmask & (cmask - 1)) != 0u;
        unsigned long long ball = __ballot(need);
        while (ball) {
            const int sx = (int)__builtin_ctzll(ball);   // lowest flagged lane
            ball &= ball - 1;
            const unsigned pm  = __shfl(cmask, sx, 64);
            const int      fhw = __shfl(phw,   sx, 64);
            const int      fb  = __shfl(pb,    sx, 64);
            const float* __restrict__ fcol = feat + (size_t)fb * C * HW + fhw;

            const int c0 = tid << 2;                     // channels 4l..4l+3
            double pf[4];
            #pragma unroll
            for (int j = 0; j < 4; ++j)
                pf[j] = (double)fcol[(size_t)(c0 + j) * HW];

            double bd = 1e300; int bi = 0;
            unsigned mm = pm;
            while (mm) {                      // ascending k, strict < tie-break
                const int k = (int)__builtin_ctz(mm);
                mm &= mm - 1;
                const float* __restrict__ ck = cent + (size_t)k * C + c0;
                double s = 0.0;
                #pragma unroll
                for (int j = 0; j < 4; ++j)
                    s = fma(pf[j], (double)ck[j], s);
                #pragma unroll
                for (int off = 1; off < 64; off <<= 1)
                    s += __shfl_xor(s, off, 64);
                const double dk = sc2d[k] - 2.0 * s;
                if (dk < bd) { bd = dk; bi = k; }
            }
            if (tid == sx) best = bi;         // all lanes agree on bi
        }

        // write the 8x8 nearest-upsampled block (R19 verbatim)
        const int w  = phw & (WF - 1);
        const int hh = phw >> 7;
        int4 v = make_int4(best, best, best, best);
        int* __restrict__ ob = out + (size_t)map * (BB * HL * WL)
                                   + (size_t)pb * (HL * WL)
                                   + (size_t)(hh * 8) * WL + (size_t)(w * 8);
        #pragma unroll
        for (int r = 0; r < 8; ++r) {
            *(int4*)(ob + (size_t)r * WL)     = v;
            *(int4*)(ob + (size_t)r * WL + 4) = v;
        }
    }
}

extern "C" void kernel_launch(void* const* d_in, const int* in_sizes, int n_in,
                              void* d_out, int out_size, void* d_ws, size_t ws_size,
                              hipStream_t stream) {
    const float* feature_s2t     = (const float*)d_in[0];
    const float* feature_target  = (const float*)d_in[1];
    // d_in[2], d_in[3]: labels — only shapes matter, unused
    const float* centroid_s2t    = (const float*)d_in[4];
    const float* centroid_target = (const float*)d_in[5];
    int* out = (int*)d_out;

    dim3 grid(32768 / 64, 2);   // (512, 2) -> 1024 blocks, 8192 waves, 8/SIMD
    dim3 block(512);
    hipLaunchKernelGGL(centroid_mask_kernel, grid, block, 0, stream,
                       feature_s2t, feature_target,
                       centroid_target, centroid_s2t, out);
}

// Round 23
// 24.249 us; speedup vs baseline: 1.0097x; 1.0097x over previous
//
#include <hip/hip_runtime.h>

// Problem constants (fixed by setup_inputs)
#define K   19
#define C   256
#define HF  64
#define WF  128
#define HW  (HF * WF)
#define BB  4
#define HL  512
#define WL  1024

// bf16-split-x3 distance error bound ~1e-3 worst-case; pixels whose top-2
// gap < TAU get the proven exact-f64 cooperative resolve.
#define TAU 0.03f

#define CPAD 264                        // halfwords per centroid row
#define DPAD 66                         // dwords per acc row
#define CHI_BYTES  (K * CPAD * 2)       // 10032 B
#define DBUF_BYTES (16 * 16 * DPAD * 4) // 67584 B (2 pxg x 4 khq x 2 tile x 16 reg)
#define POOL_BYTES DBUF_BYTES           // overlay: chi|clo (20064) inside dbuf

typedef __attribute__((ext_vector_type(8)))  short bf16x8;
typedef __attribute__((ext_vector_type(16))) float f32x16;

// R19 numerics at 2x the read width. Every variant since R4 loaded features
// at 4 B/lane = 256 B/wave-instr (256K VMEM instrs total); the 6.9 TB/s fill
// kernels move 1 KB/instr. Here lane i loads float2 = pixels {2i, 2i+1} of
// one channel -> 1 KB/wave-instr, 64K VMEM instrs (4x fewer). The pair feeds
// TWO 32x32 MFMA tiles (tile0 = even px from .x, tile1 = odd px from .y) --
// A-row m <-> pixel 2m+t, no cross-lane repack. Block = 512 thr = 8 waves =
// 2 px-groups(64px) x 4 K-quarters; grid (256,2) = 512 blocks = 2/CU
// resident, 16 waves/CU (R19's TLP). dbuf overlays dead chi/clo. B base
// includes khq*64 (R18 lesson). Epilogue/fallback: R20's proven 128-px form.
__global__ __launch_bounds__(512, 4) void centroid_mask_kernel(
    const float* __restrict__ feat0,   // feature_s2t
    const float* __restrict__ feat1,   // feature_target
    const float* __restrict__ cent0,   // centroids for map 0 (centroid_target)
    const float* __restrict__ cent1,   // centroids for map 1 (centroid_s2t)
    int* __restrict__ out)             // [2][BB][HL][WL] int32
{
    __shared__ __align__(16) unsigned char pool[POOL_BYTES];  // chi|clo -> dbuf
    __shared__ double c2p[K][8];             // exact ||c||^2 partials
    __shared__ double sc2d[K];               // exact ||c||^2 (f64)
    __shared__ float  sc2f[K];               // rounded-exact ||c||^2 (f32)

    unsigned short* __restrict__ chi = (unsigned short*)pool;
    unsigned short* __restrict__ clo = (unsigned short*)(pool + CHI_BYTES);
    float*          __restrict__ dbf = (float*)pool;   // overlay after MFMA

    const int map = blockIdx.y;
    const float* __restrict__ feat = (map == 0) ? feat0 : feat1;
    const float* __restrict__ cent = (map == 0) ? cent0 : cent1;

    const int tid  = threadIdx.x;
    const int lane = tid & 63;
    const int wv   = __builtin_amdgcn_readfirstlane(tid >> 6);   // 0..7
    const int pxg  = wv >> 2;                  // px-group: 0..1 (64 px each)
    const int khq  = wv & 3;                   // K-quarter: 0..3 (64 ch each)

    // ---- stage split centroids into LDS (coalesced) + exact ||c||^2 ----
    for (int i = tid; i < K * C; i += 512) {
        const int k = i >> 8, c = i & (C - 1);
        const unsigned u = __float_as_uint(cent[i]);
        const float r = __uint_as_float(u) - __uint_as_float(u & 0xffff0000u);
        chi[k * CPAD + c] = (unsigned short)(u >> 16);
        clo[k * CPAD + c] = (unsigned short)(__float_as_uint(r) >> 16);
    }
    if (tid < K * 8) {
        const int k = tid >> 3, sl = tid & 7;
        const float* cp = cent + k * C + sl * 32;
        double s = 0.0;
        #pragma unroll
        for (int j = 0; j < 32; ++j) { double v = (double)cp[j]; s = fma(v, v, s); }
        c2p[k][sl] = s;
    }
    __syncthreads();
    if (tid < K) {
        double s = 0.0;
        #pragma unroll
        for (int j = 0; j < 8; ++j) s += c2p[tid][j];
        sc2d[tid] = s;
        sc2f[tid] = (float)s;
    }

    // ---- main: wave = (pxg, khq); 64 px (2 tiles) x 19 k over 64 channels ----
    const int hl2 = (lane >> 5) & 1;               // k-subchunk select
    const int pg  = blockIdx.x * 128 + pxg * 64;   // group base pixel (64-aligned)
    const int hw0 = pg & (HW - 1);
    const int b   = pg >> 13;

    const float2* __restrict__ fp2 =
        (const float2*)(feat + (size_t)b * C * HW + hw0);
    const int cb0  = khq * 64 + hl2 * 8;           // A channel base
    const int bidx = min(lane & 31, 18) * CPAD + khq * 64 + hl2 * 8;  // B base

    f32x16 acc0, acc1;
    #pragma unroll
    for (int r = 0; r < 16; ++r) { acc0[r] = 0.f; acc1[r] = 0.f; }

    #pragma unroll
    for (int s = 0; s < 4; ++s) {                  // 4 K-steps of 16 channels
        float2 fv[8];
        #pragma unroll
        for (int j = 0; j < 8; ++j)                // 1 KB per wave-instruction
            fv[j] = fp2[(size_t)(cb0 + s * 16 + j) * (HW / 2) + (lane & 31)];

        union { unsigned u[4]; bf16x8 v; } ah0, al0, ah1, al1, bh, bl;
        #pragma unroll
        for (int j = 0; j < 4; ++j) {
            // tile0 (even px) from .x
            {
                const unsigned u0 = __float_as_uint(fv[2*j].x);
                const unsigned u1 = __float_as_uint(fv[2*j+1].x);
                ah0.u[j] = (u0 >> 16) | (u1 & 0xffff0000u);
                const float r0 = fv[2*j].x   - __uint_as_float(u0 & 0xffff0000u);
                const float r1 = fv[2*j+1].x - __uint_as_float(u1 & 0xffff0000u);
                al0.u[j] = (__float_as_uint(r0) >> 16)
                         | (__float_as_uint(r1) & 0xffff0000u);
            }
            // tile1 (odd px) from .y
            {
                const unsigned u0 = __float_as_uint(fv[2*j].y);
                const unsigned u1 = __float_as_uint(fv[2*j+1].y);
                ah1.u[j] = (u0 >> 16) | (u1 & 0xffff0000u);
                const float r0 = fv[2*j].y   - __uint_as_float(u0 & 0xffff0000u);
                const float r1 = fv[2*j+1].y - __uint_as_float(u1 & 0xffff0000u);
                al1.u[j] = (__float_as_uint(r0) >> 16)
                         | (__float_as_uint(r1) & 0xffff0000u);
            }
        }
        bh.v = *(const bf16x8*)&chi[bidx + s * 16];   // shared by both tiles
        bl.v = *(const bf16x8*)&clo[bidx + s * 16];

        acc0 = __builtin_amdgcn_mfma_f32_32x32x16_bf16(ah0.v, bh.v, acc0, 0, 0, 0);
        acc0 = __builtin_amdgcn_mfma_f32_32x32x16_bf16(ah0.v, bl.v, acc0, 0, 0, 0);
        acc0 = __builtin_amdgcn_mfma_f32_32x32x16_bf16(al0.v, bh.v, acc0, 0, 0, 0);
        acc1 = __builtin_amdgcn_mfma_f32_32x32x16_bf16(ah1.v, bh.v, acc1, 0, 0, 0);
        acc1 = __builtin_amdgcn_mfma_f32_32x32x16_bf16(ah1.v, bl.v, acc1, 0, 0, 0);
        acc1 = __builtin_amdgcn_mfma_f32_32x32x16_bf16(al1.v, bh.v, acc1, 0, 0, 0);
    }

    __syncthreads();   // all waves done READING chi/clo -> pool reusable

    // dump: slot (pxg,khq,tile); element (reg,lane) stored at [reg][hl2*32+(lane&31)]
    {
        const int slot0 = ((pxg * 4 + khq) * 2 + 0) * 16;
        const int slot1 = ((pxg * 4 + khq) * 2 + 1) * 16;
        float* d0 = &dbf[slot0 * DPAD + hl2 * 32 + (lane & 31)];
        float* d1 = &dbf[slot1 * DPAD + hl2 * 32 + (lane & 31)];
        #pragma unroll
        for (int r = 0; r < 16; ++r) {
            d0[r * DPAD] = acc0[r];
            d1[r * DPAD] = acc1[r];
        }
    }
    __syncthreads();

    // ---- epilogue: waves 0+1 own 128 px (R20's proven form, disjoint ballots) ----
    if (tid < 128) {
        const int el  = tid & 63;          // lane within epilogue wave
        const int ep  = tid;               // pixel index within block: 0..127
        const int epg = ep >> 6;           // px-group
        const int px  = ep & 63;           // pixel within group
        const int tl  = px & 1;            // tile: even/odd pixel
        const int m   = px >> 1;           // row within 32x32 tile
        const int h   = (m >> 2) & 1;
        const int reg = (m & 3) | ((m >> 3) << 2);
        const int bse = h * 32;

        const int ppx = blockIdx.x * 128 + ep;
        const int phw = ppx & (HW - 1);
        const int pb  = ppx >> 13;

        float d[K];
        #pragma unroll
        for (int k = 0; k < K; ++k) {
            const float s =
                (dbf[(((epg*4+0)*2+tl)*16 + reg) * DPAD + bse + k]
               + dbf[(((epg*4+1)*2+tl)*16 + reg) * DPAD + bse + k])
              + (dbf[(((epg*4+2)*2+tl)*16 + reg) * DPAD + bse + k]
               + dbf[(((epg*4+3)*2+tl)*16 + reg) * DPAD + bse + k]);
            d[k] = sc2f[k] - 2.0f * s;
        }
        int best = 0; float m1 = d[0];
        #pragma unroll
        for (int k = 1; k < K; ++k) if (d[k] < m1) { m1 = d[k]; best = k; }

        unsigned cmask = 0u;
        #pragma unroll
        for (int k = 0; k < K; ++k) if (d[k] - m1 < TAU) cmask |= (1u << k);

        // cooperative exact-f64 resolve of flagged pixels (proven, R8)
        const bool need = (cmask & (cmask - 1)) != 0u;
        unsigned long long ball = __ballot(need);
        while (ball) {
            const int sx = (int)__builtin_ctzll(ball);   // lowest flagged lane
            ball &= ball - 1;
            const unsigned pm  = __shfl(cmask, sx, 64);
            const int      fhw = __shfl(phw,   sx, 64);
            const int      fb  = __shfl(pb,    sx, 64);
            const float* __restrict__ fcol = feat + (size_t)fb * C * HW + fhw;

            const int c0 = el << 2;                      // channels 4l..4l+3
            double pf[4];
            #pragma unroll
            for (int j = 0; j < 4; ++j)
                pf[j] = (double)fcol[(size_t)(c0 + j) * HW];

            double bd = 1e300; int bi = 0;
            unsigned mm = pm;
            while (mm) {                      // ascending k, strict < tie-break
                const int k = (int)__builtin_ctz(mm);
                mm &= mm - 1;
                const float* __restrict__ ck = cent + (size_t)k * C + c0;
                double s = 0.0;
                #pragma unroll
                for (int j = 0; j < 4; ++j)
                    s = fma(pf[j], (double)ck[j], s);
                #pragma unroll
                for (int off = 1; off < 64; off <<= 1)
                    s += __shfl_xor(s, off, 64);
                const double dk = sc2d[k] - 2.0 * s;
                if (dk < bd) { bd = dk; bi = k; }
            }
            if (el == sx) best = bi;          // all lanes agree on bi
        }

        // write the 8x8 nearest-upsampled block
        const int w  = phw & (WF - 1);
        const int hh = phw >> 7;
        int4 v = make_int4(best, best, best, best);
        int* __restrict__ ob = out + (size_t)map * (BB * HL * WL)
                                   + (size_t)pb * (HL * WL)
                                   + (size_t)(hh * 8) * WL + (size_t)(w * 8);
        #pragma unroll
        for (int r = 0; r < 8; ++r) {
            *(int4*)(ob + (size_t)r * WL)     = v;
            *(int4*)(ob + (size_t)r * WL + 4) = v;
        }
    }
}

extern "C" void kernel_launch(void* const* d_in, const int* in_sizes, int n_in,
                              void* d_out, int out_size, void* d_ws, size_t ws_size,
                              hipStream_t stream) {
    const float* feature_s2t     = (const float*)d_in[0];
    const float* feature_target  = (const float*)d_in[1];
    // d_in[2], d_in[3]: labels — only shapes matter, unused
    const float* centroid_s2t    = (const float*)d_in[4];
    const float* centroid_target = (const float*)d_in[5];
    int* out = (int*)d_out;

    // 128 px per block -> grid (256, 2) = 512 blocks, 2/CU, 16 waves/CU
    dim3 grid(32768 / 128, 2);
    dim3 block(512);
    hipLaunchKernelGGL(centroid_mask_kernel, grid, block, 0, stream,
                       feature_s2t, feature_target,
                       centroid_target, centroid_s2t, out);
}

// Round 24
// 22.756 us; speedup vs baseline: 1.0759x; 1.0656x over previous
//
#include <hip/hip_runtime.h>

// Problem constants (fixed by setup_inputs)
#define K   19
#define C   256
#define HF  64
#define WF  128
#define HW  (HF * WF)
#define BB  4
#define HL  512
#define WL  1024

// bf16-split-x3 distance error bound ~1e-3 worst-case; pixels whose top-2
// gap < TAU get the exact-f64 cooperative resolve (computes sum (f-c)^2
// from scratch -- c2 accuracy only affects the FLAG margin, so c2 is f32).
#define TAU 0.03f

#define CPAD 264    // halfwords per centroid row: 528 B = 33 x 16 B
#define DPAD 66     // dwords per acc row

typedef __attribute__((ext_vector_type(8)))  short bf16x8;
typedef __attribute__((ext_vector_type(16))) float f32x16;

// R19 (best: 22.7us) minus its serial prologue overheads:
//  - c2 computed in f32 (was: 152 threads x 32-deep DEPENDENT f64 FMA chain
//    ~256 serial cycles/block at half-rate f64 + f64 reduce). c2 only sets
//    the near-tie flag margin (TAU=0.03 >> 1e-4 f32 c2 error); the fallback
//    recomputes distances from scratch.
//  - fallback in (f-c)^2 form (R11 resolver math, proven absmax=0): no sc2d.
// Main loop / layouts / epilogue: R19 verbatim.
__global__ __launch_bounds__(256, 4) void centroid_mask_kernel(
    const float* __restrict__ feat0,   // feature_s2t
    const float* __restrict__ feat1,   // feature_target
    const float* __restrict__ cent0,   // centroids for map 0 (centroid_target)
    const float* __restrict__ cent1,   // centroids for map 1 (centroid_s2t)
    int* __restrict__ out)             // [2][BB][HL][WL] int32
{
    __shared__ __align__(16) unsigned short chi[K * CPAD];  // centroid hi bf16
    __shared__ __align__(16) unsigned short clo[K * CPAD];  // centroid lo bf16
    __shared__ float  dbuf[2][2][16][DPAD];  // [tile][khalf][reg][32h+k]
    __shared__ float  c2p[K][8];             // f32 ||c||^2 partials
    __shared__ float  sc2f[K];               // f32 ||c||^2

    const int map = blockIdx.y;
    const float* __restrict__ feat = (map == 0) ? feat0 : feat1;
    const float* __restrict__ cent = (map == 0) ? cent0 : cent1;

    const int tid  = threadIdx.x;
    const int lane = tid & 63;
    const int wv   = __builtin_amdgcn_readfirstlane(tid >> 6);   // 0..3, uniform

    // ---- stage split centroids into LDS (coalesced) + f32 ||c||^2 ----
    for (int i = tid; i < K * C; i += 256) {
        const int k = i >> 8, c = i & (C - 1);
        const unsigned u = __float_as_uint(cent[i]);
        const float r = __uint_as_float(u) - __uint_as_float(u & 0xffff0000u);
        chi[k * CPAD + c] = (unsigned short)(u >> 16);
        clo[k * CPAD + c] = (unsigned short)(__float_as_uint(r) >> 16);
    }
    if (tid < K * 8) {
        const int k = tid >> 3, sl = tid & 7;
        const float* cp = cent + k * C + sl * 32;
        float s0 = 0.f, s1 = 0.f, s2 = 0.f, s3 = 0.f;
        #pragma unroll
        for (int j = 0; j < 8; ++j) {
            s0 = fmaf(cp[4*j+0], cp[4*j+0], s0);
            s1 = fmaf(cp[4*j+1], cp[4*j+1], s1);
            s2 = fmaf(cp[4*j+2], cp[4*j+2], s2);
            s3 = fmaf(cp[4*j+3], cp[4*j+3], s3);
        }
        c2p[k][sl] = (s0 + s1) + (s2 + s3);
    }
    __syncthreads();
    if (tid < K) {
        float s = 0.f;
        #pragma unroll
        for (int j = 0; j < 8; ++j) s += c2p[tid][j];
        sc2f[tid] = s;
    }

    // ---- main: wave = (tile, khalf); 32 px x 19 k, K-half = 128 ch ----
    const int tile = wv >> 1, kh = wv & 1;
    const int hl2  = (lane >> 5) & 1;              // k-subchunk select
    const int pp   = blockIdx.x * 64 + tile * 32 + (lane & 31);
    const int hw   = pp & (HW - 1);
    const int b    = pp >> 13;

    const float* __restrict__ fp = feat + (size_t)b * C * HW + hw;
    const int cb0  = kh * 128 + hl2 * 8;           // A channel base for this lane
    const int bidx = min(lane & 31, 18) * CPAD + kh * 128 + hl2 * 8;  // B base

    f32x16 acc;
    #pragma unroll
    for (int r = 0; r < 16; ++r) acc[r] = 0.f;

    #pragma unroll
    for (int s = 0; s < 8; ++s) {                  // 8 K-steps of 16
        const int cb = cb0 + s * 16;
        float fv[8];
        #pragma unroll
        for (int j = 0; j < 8; ++j)
            fv[j] = fp[(size_t)(cb + j) * HW];     // coalesced over lanes 0-31

        union { unsigned u[4]; bf16x8 v; } ah, al, bh, bl;
        #pragma unroll
        for (int j = 0; j < 4; ++j) {
            const unsigned u0 = __float_as_uint(fv[2*j]);
            const unsigned u1 = __float_as_uint(fv[2*j+1]);
            ah.u[j] = (u0 >> 16) | (u1 & 0xffff0000u);           // hi (truncate)
            const float r0 = fv[2*j]   - __uint_as_float(u0 & 0xffff0000u);
            const float r1 = fv[2*j+1] - __uint_as_float(u1 & 0xffff0000u);
            al.u[j] = (__float_as_uint(r0) >> 16)
                    | (__float_as_uint(r1) & 0xffff0000u);       // lo (truncate)
        }
        bh.v = *(const bf16x8*)&chi[bidx + s * 16];
        bl.v = *(const bf16x8*)&clo[bidx + s * 16];

        acc = __builtin_amdgcn_mfma_f32_32x32x16_bf16(ah.v, bh.v, acc, 0, 0, 0);
        acc = __builtin_amdgcn_mfma_f32_32x32x16_bf16(ah.v, bl.v, acc, 0, 0, 0);
        acc = __builtin_amdgcn_mfma_f32_32x32x16_bf16(al.v, bh.v, acc, 0, 0, 0);
    }

    // dump acc: element (reg, lane) = D[px=(reg&3)+8(reg>>2)+4(lane>>5)][k=lane&31]
    {
        float* dst = &dbuf[tile][kh][0][hl2 * 32 + (lane & 31)];
        #pragma unroll
        for (int r = 0; r < 16; ++r) dst[r * DPAD] = acc[r];
    }
    __syncthreads();

    // ---- epilogue: wave 0, lane = pixel (both tiles); R19 pattern verbatim ----
    if (tid < 64) {
        const int l   = tid;
        const int tl  = l >> 5, px = l & 31;
        const int h   = (px >> 2) & 1;
        const int reg = (px & 3) | ((px >> 3) << 2);
        const int bse = h * 32;

        const int ppx = blockIdx.x * 64 + l;       // tl*32+px == l
        const int phw = ppx & (HW - 1);
        const int pb  = ppx >> 13;

        float d[K];
        #pragma unroll
        for (int k = 0; k < K; ++k) {
            const float s = dbuf[tl][0][reg][bse + k] + dbuf[tl][1][reg][bse + k];
            d[k] = sc2f[k] - 2.0f * s;
        }
        int best = 0; float m1 = d[0];
        #pragma unroll
        for (int k = 1; k < K; ++k) if (d[k] < m1) { m1 = d[k]; best = k; }

        unsigned cmask = 0u;
        #pragma unroll
        for (int k = 0; k < K; ++k) if (d[k] - m1 < TAU) cmask |= (1u << k);

        // cooperative exact-f64 resolve of flagged pixels: sum (f-c)^2 form
        // (R11 resolver math -- no c2 table needed, exact argmin)
        const bool need = (cmask & (cmask - 1)) != 0u;
        unsigned long long ball = __ballot(need);
        while (ball) {
            const int sx = (int)__builtin_ctzll(ball);   // lowest flagged lane
            ball &= ball - 1;
            const unsigned pm  = __shfl(cmask, sx, 64);
            const int      fhw = __shfl(phw,   sx, 64);
            const int      fb  = __shfl(pb,    sx, 64);
            const float* __restrict__ fcol = feat + (size_t)fb * C * HW + fhw;

            const int c0 = tid << 2;                     // channels 4l..4l+3
            double pf[4];
            #pragma unroll
            for (int j = 0; j < 4; ++j)
                pf[j] = (double)fcol[(size_t)(c0 + j) * HW];

            double bd = 1e300; int bi = 0;
            unsigned mm = pm;
            while (mm) {                      // ascending k, strict < tie-break
                const int k = (int)__builtin_ctz(mm);
                mm &= mm - 1;
                const float4 cc = *(const float4*)(cent + (size_t)k * C + c0);
                double s = 0.0, t;
                t = pf[0] - (double)cc.x; s = fma(t, t, s);
                t = pf[1] - (double)cc.y; s = fma(t, t, s);
                t = pf[2] - (double)cc.z; s = fma(t, t, s);
                t = pf[3] - (double)cc.w; s = fma(t, t, s);
                #pragma unroll
                for (int off = 1; off < 64; off <<= 1)
                    s += __shfl_xor(s, off, 64);
                if (s < bd) { bd = s; bi = k; }
            }
            if (tid == sx) best = bi;         // all lanes agree on bi
        }

        // write the 8x8 nearest-upsampled block (R19 verbatim)
        const int w  = phw & (WF - 1);
        const int hh = phw >> 7;
        int4 v = make_int4(best, best, best, best);
        int* __restrict__ ob = out + (size_t)map * (BB * HL * WL)
                                   + (size_t)pb * (HL * WL)
                                   + (size_t)(hh * 8) * WL + (size_t)(w * 8);
        #pragma unroll
        for (int r = 0; r < 8; ++r) {
            *(int4*)(ob + (size_t)r * WL)     = v;
            *(int4*)(ob + (size_t)r * WL + 4) = v;
        }
    }
}

extern "C" void kernel_launch(void* const* d_in, const int* in_sizes, int n_in,
                              void* d_out, int out_size, void* d_ws, size_t ws_size,
                              hipStream_t stream) {
    const float* feature_s2t     = (const float*)d_in[0];
    const float* feature_target  = (const float*)d_in[1];
    // d_in[2], d_in[3]: labels — only shapes matter, unused
    const float* centroid_s2t    = (const float*)d_in[4];
    const float* centroid_target = (const float*)d_in[5];
    int* out = (int*)d_out;

    dim3 grid(32768 / 64, 2);   // (512, 2) -> 1024 blocks, 4/CU
    dim3 block(256);
    hipLaunchKernelGGL(centroid_mask_kernel, grid, block, 0, stream,
                       feature_s2t, feature_target,
                       centroid_target, centroid_s2t, out);
}